// Round 4
// baseline (512.377 us; speedup 1.0000x reference)
//
#include <hip/hip_runtime.h>
#include <cmath>

#define B_    8
#define T_    256
#define V_    32000
#define E_    512
#define OOV_  100
#define VE_   (V_ + OOV_)               // 32100
#define ROWS_ (B_ * T_)                 // 2048
#define NV4_  (V_ / 4)                  // 8000 float4 per row
#define PAD4_ (OOV_ / 4)                // 25 float4 of zero padding
#define TOTAL_ ((size_t)ROWS_ * VE_)    // 65,740,800 floats

// One block (1024 threads) per (b,t) row. Fully fused:
//  - pgen dot(2048) + sigmoid
//  - register-resident softmax over V=32000 (logits read from HBM once)
//  - blended write pgen*softmax + OOV pad zeroing
//  - native-f32-atomic scatter of (1-pgen)*attn into the just-written
//    (L2-hot) row. Intra-block only: __syncthreads() orders the plain
//    stores (vmcnt-drained to L2) before the atomics.
__global__ __launch_bounds__(1024) void pg_fused_kernel(
    const float* __restrict__ logits,
    const float* __restrict__ attn,   // (rows, 512)
    const float* __restrict__ ctx,    // (rows, 512)
    const float* __restrict__ hid,    // (rows, 1024)
    const float* __restrict__ dec,    // (rows, 512)
    const int*   __restrict__ enc,    // (B, 512)
    const float* __restrict__ pw,     // (2048,)
    const float* __restrict__ pb,     // (1,)
    float* __restrict__ out_total,    // (rows, 32100)
    float* __restrict__ out_pgen)     // (rows,)
{
  const int row  = blockIdx.x;
  const int tid  = threadIdx.x;
  const int lane = tid & 63;
  const int wid  = tid >> 6;          // 16 waves per block
  __shared__ float redA[16];
  __shared__ float redB[16];

  // ---------------- prefetch scatter operands (hide latency) ----------------
  float att_v = 0.f;
  int   att_i = 0;
  if (tid < E_) {
    att_v = attn[row * E_ + tid];
    att_i = enc[((row >> 8) << 9) + tid];   // b = row / T_, T_ = 256
  }

  // ---------------- pgen: dot(pre, w) over 2048 features ----------------
  float acc = 0.f;
  #pragma unroll
  for (int k = 0; k < 2; ++k) {
    const int f = tid + (k << 10);
    float pv;
    if (f < 512)       pv = ctx[row * 512 + f];
    else if (f < 1536) pv = hid[row * 1024 + (f - 512)];
    else               pv = dec[row * 512 + (f - 1536)];
    acc += pv * pw[f];
  }
  #pragma unroll
  for (int o = 32; o > 0; o >>= 1) acc += __shfl_xor(acc, o);
  if (lane == 0) redA[wid] = acc;
  __syncthreads();
  if (tid < 16) {
    float x = redA[tid];
    #pragma unroll
    for (int o = 8; o > 0; o >>= 1) x += __shfl_xor(x, o);
    if (tid == 0) redA[0] = x;
  }
  __syncthreads();
  const float pgen = 1.f / (1.f + __expf(-(redA[0] + pb[0])));
  __syncthreads();   // redA reused below

  // ---------------- softmax stats, row held in registers ----------------
  const float4* lrow = (const float4*)(logits + (size_t)row * V_);
  float4 v[8];
  float m = -3.0e38f;
  #pragma unroll
  for (int k = 0; k < 7; ++k) {
    const float4 x = lrow[tid + (k << 10)];
    v[k] = x;
    m = fmaxf(m, fmaxf(fmaxf(x.x, x.y), fmaxf(x.z, x.w)));
  }
  if (tid < NV4_ - 7168) {             // tail: 8000 - 7*1024 = 832
    const float4 x = lrow[tid + 7168];
    v[7] = x;
    m = fmaxf(m, fmaxf(fmaxf(x.x, x.y), fmaxf(x.z, x.w)));
  }
  float s = 0.f;
  #pragma unroll
  for (int k = 0; k < 8; ++k) {
    if (k < 7 || tid < NV4_ - 7168) {
      float4 x = v[k];
      x.x = __expf(x.x - m); x.y = __expf(x.y - m);
      x.z = __expf(x.z - m); x.w = __expf(x.w - m);
      s += x.x + x.y + x.z + x.w;
      v[k] = x;                        // stash exp(x - m_local)
    }
  }
  // wave-level (m,s) online merge
  #pragma unroll
  for (int o = 32; o > 0; o >>= 1) {
    const float om = __shfl_xor(m, o);
    const float os = __shfl_xor(s, o);
    const float nm = fmaxf(m, om);
    s = s * __expf(m - nm) + os * __expf(om - nm);
    m = nm;
  }
  if (lane == 0) { redA[wid] = m; redB[wid] = s; }
  __syncthreads();
  if (tid < 16) {
    float mm = redA[tid], ss = redB[tid];
    #pragma unroll
    for (int o = 8; o > 0; o >>= 1) {
      const float om = __shfl_xor(mm, o);
      const float os = __shfl_xor(ss, o);
      const float nm = fmaxf(mm, om);
      ss = ss * __expf(mm - nm) + os * __expf(om - nm);
      mm = nm;
    }
    if (tid == 0) { redA[0] = mm; redB[0] = ss; }
  }
  __syncthreads();
  const float M = redA[0];
  const float S = redB[0];
  // out = exp(x - M)/S * pgen = stash * exp(m_local - M)/S * pgen
  const float scale = pgen * __expf(m - M) / S;

  // ---------------- blended write + OOV pad zeroing ----------------
  float4* orow = (float4*)(out_total + (size_t)row * VE_);
  #pragma unroll
  for (int k = 0; k < 8; ++k) {
    if (k < 7 || tid < NV4_ - 7168) {
      float4 x = v[k];
      x.x *= scale; x.y *= scale; x.z *= scale; x.w *= scale;
      orow[tid + (k << 10)] = x;
    }
  }
  if (tid < PAD4_) orow[NV4_ + tid] = make_float4(0.f, 0.f, 0.f, 0.f);
  if (tid == 0) out_pgen[row] = pgen;

  // ---------------- fused scatter into own (L2-hot) row ----------------
  __syncthreads();   // order plain stores (incl. pad) before atomics
  if (tid < E_) {
    unsafeAtomicAdd(out_total + (size_t)row * VE_ + att_i,
                    (1.f - pgen) * att_v);
  }
}

extern "C" void kernel_launch(void* const* d_in, const int* in_sizes, int n_in,
                              void* d_out, int out_size, void* d_ws, size_t ws_size,
                              hipStream_t stream) {
  const float* logits = (const float*)d_in[0];   // (8,256,32000)
  const float* attn   = (const float*)d_in[1];   // (8,256,512)
  const float* hid    = (const float*)d_in[2];   // (8,256,1024)
  const float* dec    = (const float*)d_in[3];   // (8,256,512)
  const float* ctx    = (const float*)d_in[4];   // (8,256,512)
  const int*   enc    = (const int*)d_in[5];     // (8,512)
  const float* pw     = (const float*)d_in[6];   // (1,2048)
  const float* pb     = (const float*)d_in[7];   // (1,)

  float* out_total = (float*)d_out;
  float* out_pgen  = out_total + TOTAL_;

  pg_fused_kernel<<<ROWS_, 1024, 0, stream>>>(
      logits, attn, ctx, hid, dec, enc, pw, pb, out_total, out_pgen);
}

// Round 5
// 497.829 us; speedup vs baseline: 1.0292x; 1.0292x over previous
//
#include <hip/hip_runtime.h>
#include <cmath>

#define B_    8
#define T_    256
#define V_    32000
#define E_    512
#define OOV_  100
#define VE_   (V_ + OOV_)               // 32100
#define ROWS_ (B_ * T_)                 // 2048
#define NV4_  (V_ / 4)                  // 8000 float4 per row
#define TAIL_ (NV4_ - 7 * 1024)         // 832 threads have an 8th float4
#define PAD4_ (OOV_ / 4)                // 25 float4 of zero padding
#define TOTAL_ ((size_t)ROWS_ * VE_)    // 65,740,800 floats

// One block (1024 threads) per (b,t) row. Fully fused, TWO-PASS softmax:
//  pass 1: stream logits with ONLINE per-thread (m,s) — no register stash,
//          so loads pipeline deeply even under a tight VGPR budget.
//  pass 2: re-read logits (row is L2/L3-hot: L3=256MB holds all of it),
//          write pgen*exp(x-M)/S. Pure streaming, minimal live state.
//  plus: fused pgen dot+sigmoid, OOV pad zeroing, and native-f32-atomic
//  scatter of (1-pgen)*attn into the just-written (L2-hot) row.
__global__ __launch_bounds__(1024) void pg_fused_kernel(
    const float* __restrict__ logits,
    const float* __restrict__ attn,   // (rows, 512)
    const float* __restrict__ ctx,    // (rows, 512)
    const float* __restrict__ hid,    // (rows, 1024)
    const float* __restrict__ dec,    // (rows, 512)
    const int*   __restrict__ enc,    // (B, 512)
    const float* __restrict__ pw,     // (2048,)
    const float* __restrict__ pb,     // (1,)
    float* __restrict__ out_total,    // (rows, 32100)
    float* __restrict__ out_pgen)     // (rows,)
{
  const int row  = blockIdx.x;
  const int tid  = threadIdx.x;
  const int lane = tid & 63;
  const int wid  = tid >> 6;          // 16 waves per block
  __shared__ float redA[16];
  __shared__ float redB[16];

  // -------- prefetch scatter operands (hide latency under everything) -----
  float att_v = 0.f;
  int   att_i = 0;
  if (tid < E_) {
    att_v = attn[row * E_ + tid];
    att_i = enc[((row >> 8) << 9) + tid];   // b = row / T_, T_ = 256
  }

  // ---------------- pgen: dot(pre, w) over 2048 features ----------------
  float acc = 0.f;
  #pragma unroll
  for (int k = 0; k < 2; ++k) {
    const int f = tid + (k << 10);
    float pv;
    if (f < 512)       pv = ctx[row * 512 + f];
    else if (f < 1536) pv = hid[row * 1024 + (f - 512)];
    else               pv = dec[row * 512 + (f - 1536)];
    acc += pv * pw[f];
  }
  #pragma unroll
  for (int o = 32; o > 0; o >>= 1) acc += __shfl_xor(acc, o);
  if (lane == 0) redA[wid] = acc;
  __syncthreads();
  if (tid < 16) {
    float x = redA[tid];
    #pragma unroll
    for (int o = 8; o > 0; o >>= 1) x += __shfl_xor(x, o);
    if (tid == 0) redA[0] = x;
  }
  __syncthreads();
  const float pgen = 1.f / (1.f + __expf(-(redA[0] + pb[0])));
  __syncthreads();   // redA reused below

  // -------- pass 1: online (m,s) over the row — no stash ----------------
  const float4* lrow = (const float4*)(logits + (size_t)row * V_);
  float m = -3.0e38f;
  float s = 0.f;
  #pragma unroll
  for (int k = 0; k < 7; ++k) {
    const float4 x = lrow[tid + (k << 10)];
    const float xm = fmaxf(fmaxf(x.x, x.y), fmaxf(x.z, x.w));
    const float nm = fmaxf(m, xm);
    const float e0 = __expf(x.x - nm), e1 = __expf(x.y - nm);
    const float e2 = __expf(x.z - nm), e3 = __expf(x.w - nm);
    s = s * __expf(m - nm) + ((e0 + e1) + (e2 + e3));
    m = nm;
  }
  if (tid < TAIL_) {
    const float4 x = lrow[tid + 7168];
    const float xm = fmaxf(fmaxf(x.x, x.y), fmaxf(x.z, x.w));
    const float nm = fmaxf(m, xm);
    const float e0 = __expf(x.x - nm), e1 = __expf(x.y - nm);
    const float e2 = __expf(x.z - nm), e3 = __expf(x.w - nm);
    s = s * __expf(m - nm) + ((e0 + e1) + (e2 + e3));
    m = nm;
  }

  // wave-level (m,s) merge
  #pragma unroll
  for (int o = 32; o > 0; o >>= 1) {
    const float om = __shfl_xor(m, o);
    const float os = __shfl_xor(s, o);
    const float nm = fmaxf(m, om);
    s = s * __expf(m - nm) + os * __expf(om - nm);
    m = nm;
  }
  if (lane == 0) { redA[wid] = m; redB[wid] = s; }
  __syncthreads();
  if (tid < 16) {
    float mm = redA[tid], ss = redB[tid];
    #pragma unroll
    for (int o = 8; o > 0; o >>= 1) {
      const float om = __shfl_xor(mm, o);
      const float os = __shfl_xor(ss, o);
      const float nm = fmaxf(mm, om);
      ss = ss * __expf(mm - nm) + os * __expf(om - nm);
      mm = nm;
    }
    if (tid == 0) { redA[0] = mm; redB[0] = ss; }
  }
  __syncthreads();
  const float M = redA[0];
  const float scale = pgen / redB[0];   // pgen / S

  // -------- pass 2: re-read (L2/L3-hot) row, write blended probs --------
  float4* orow = (float4*)(out_total + (size_t)row * VE_);
  #pragma unroll
  for (int k = 0; k < 7; ++k) {
    const int i = tid + (k << 10);
    const float4 x = lrow[i];
    float4 y;
    y.x = scale * __expf(x.x - M);
    y.y = scale * __expf(x.y - M);
    y.z = scale * __expf(x.z - M);
    y.w = scale * __expf(x.w - M);
    orow[i] = y;
  }
  if (tid < TAIL_) {
    const float4 x = lrow[tid + 7168];
    float4 y;
    y.x = scale * __expf(x.x - M);
    y.y = scale * __expf(x.y - M);
    y.z = scale * __expf(x.z - M);
    y.w = scale * __expf(x.w - M);
    orow[tid + 7168] = y;
  }
  if (tid < PAD4_) orow[NV4_ + tid] = make_float4(0.f, 0.f, 0.f, 0.f);
  if (tid == 0) out_pgen[row] = pgen;

  // ---------------- fused scatter into own (L2-hot) row ----------------
  __syncthreads();   // order plain stores (incl. pad) before atomics
  if (tid < E_) {
    unsafeAtomicAdd(out_total + (size_t)row * VE_ + att_i,
                    (1.f - pgen) * att_v);
  }
}

extern "C" void kernel_launch(void* const* d_in, const int* in_sizes, int n_in,
                              void* d_out, int out_size, void* d_ws, size_t ws_size,
                              hipStream_t stream) {
  const float* logits = (const float*)d_in[0];   // (8,256,32000)
  const float* attn   = (const float*)d_in[1];   // (8,256,512)
  const float* hid    = (const float*)d_in[2];   // (8,256,1024)
  const float* dec    = (const float*)d_in[3];   // (8,256,512)
  const float* ctx    = (const float*)d_in[4];   // (8,256,512)
  const int*   enc    = (const int*)d_in[5];     // (8,512)
  const float* pw     = (const float*)d_in[6];   // (1,2048)
  const float* pb     = (const float*)d_in[7];   // (1,)

  float* out_total = (float*)d_out;
  float* out_pgen  = out_total + TOTAL_;

  pg_fused_kernel<<<ROWS_, 1024, 0, stream>>>(
      logits, attn, ctx, hid, dec, enc, pw, pb, out_total, out_pgen);
}